// Round 2
// baseline (266.775 us; speedup 1.0000x reference)
//
#include <hip/hip_runtime.h>

#define BN 8
#define NN 4096
#define DD 256   // D_FULL
#define MM 256   // num features
#define DV 256   // value dim
#define CHUNK 256
#define NC (NN / CHUNK)   // 16 chunks per batch

using f32x4 = __attribute__((ext_vector_type(4))) float;
using s16x8 = __attribute__((ext_vector_type(8))) short;

#define MFMA16(a, b, c) __builtin_amdgcn_mfma_f32_16x16x32_bf16(a, b, c, 0, 0, 0)

__device__ __forceinline__ unsigned short f2bf(float x) {
    union { float f; unsigned int u; } v; v.f = x;
    unsigned int r = v.u + 0x7FFF + ((v.u >> 16) & 1);   // RNE
    return (unsigned short)(r >> 16);
}
__device__ __forceinline__ float bf2f(unsigned short u) {
    union { unsigned int u; float f; } v; v.u = ((unsigned int)u) << 16;
    return v.f;
}

// fp32 -> (hi: truncated bf16, lo: RNE bf16 of remainder); hi+lo ~ 2^-17 rel err
__device__ __forceinline__ void split8(const float4 xa, const float4 xb,
                                       s16x8& ah, s16x8& al)
{
    const float xs[8] = {xa.x, xa.y, xa.z, xa.w, xb.x, xb.y, xb.z, xb.w};
#pragma unroll
    for (int j = 0; j < 8; ++j) {
        union { float f; unsigned u; } v; v.f = xs[j];
        const unsigned hm = v.u & 0xFFFF0000u;
        union { unsigned u; float f; } hv; hv.u = hm;
        ah[j] = (short)(hm >> 16);
        al[j] = (short)f2bf(xs[j] - hv.f);
    }
}

// ---------------------------------------------------------------------------
// K0: omega fp32 [256][256] -> hi/lo bf16 pair (row-major, B-operand ready)
// ---------------------------------------------------------------------------
__global__ __launch_bounds__(256) void omconv(
    const float* __restrict__ Om, unsigned short* __restrict__ OmH,
    unsigned short* __restrict__ OmL)
{
    const int i = blockIdx.x * 256 + threadIdx.x;
    const float4 v = *(const float4*)(Om + (size_t)i * 4);
    const float xs[4] = {v.x, v.y, v.z, v.w};
    unsigned short h[4], l[4];
#pragma unroll
    for (int j = 0; j < 4; ++j) {
        h[j] = f2bf(xs[j]);
        l[j] = f2bf(xs[j] - bf2f(h[j]));
    }
    *(uint2*)(OmH + (size_t)i * 4) = *(uint2*)h;
    *(uint2*)(OmL + (size_t)i * 4) = *(uint2*)l;
}

// ---------------------------------------------------------------------------
// K1 (fused Q+K): phi = exp(X@Om^T - rowmax)/16 via bf16 MFMA hi/lo (3 terms).
// v4: 32-row blocks (LDS 34 KB -> 4 blocks/CU, occupancy 2x), X converted to
// hi/lo bf16 ONCE at staging (reg-staged), K-loop is pure ds_read+MFMA.
// Blocks 0..1023 = K path (also writes PhiT + per-chunk Z); 1024..2047 = Q.
// ---------------------------------------------------------------------------
__global__ __launch_bounds__(256, 4) void phi_fused(
    const float* __restrict__ Qp, const float* __restrict__ Kp,
    const unsigned short* __restrict__ OmH, const unsigned short* __restrict__ OmL,
    unsigned short* __restrict__ PhiQ, unsigned short* __restrict__ PhiK,
    unsigned short* __restrict__ PhiT, float* __restrict__ Zp)
{
    const int tid = threadIdx.x;
    const int w = tid >> 6;
    const int lane = tid & 63;
    const int col = lane & 15, quad = lane >> 4;
    const bool kpath = blockIdx.x < 1024;
    const int id = kpath ? blockIdx.x : (blockIdx.x - 1024);
    const float* __restrict__ X = kpath ? Kp : Qp;
    unsigned short* __restrict__ Phi = kpath ? PhiK : PhiQ;
    const long r0 = (long)id * 32;

    __shared__ __align__(16) short AhS[32][264];   // 16896 B  (pitch 264 shorts)
    __shared__ __align__(16) short AlS[32][264];   // 16896 B
    __shared__ float rowmax_s[32];
    float (*red)[68] = (float(*)[68])AhS;                     // epilogue alias (Ah dead)
    unsigned short (*P)[264] = (unsigned short(*)[264])AlS;   // epilogue alias (Al dead)
    unsigned int* P32 = (unsigned int*)AlS;

    // ---- stage: each wave loads+converts its 8 rows (2 rows x 4 iters)
    {
        const int rsub = lane >> 5;       // 0..1
        const int cc = lane & 31;         // 8-float column group
        float4 va[4], vb[4];
#pragma unroll
        for (int j = 0; j < 4; ++j) {
            const int row = w * 8 + j * 2 + rsub;
            const float* p = X + (r0 + row) * DD + cc * 8;
            va[j] = *(const float4*)p;
            vb[j] = *(const float4*)(p + 4);
        }
#pragma unroll
        for (int j = 0; j < 4; ++j) {
            const int row = w * 8 + j * 2 + rsub;
            s16x8 ah, al;
            split8(va[j], vb[j], ah, al);
            *(s16x8*)&AhS[row][cc * 8] = ah;
            *(s16x8*)&AlS[row][cc * 8] = al;
        }
    }

    // ---- B-frag prefetch for kt=0 (issued before barrier, lands during it)
    f32x4 acc[2][4] = {};
    s16x8 bh0[4], bl0[4], bh1[4], bl1[4];
#pragma unroll
    for (int ct = 0; ct < 4; ++ct) {
        const size_t off = (size_t)(w * 64 + ct * 16 + col) * DD + quad * 8;
        bh0[ct] = *(const s16x8*)(OmH + off);
        bl0[ct] = *(const s16x8*)(OmL + off);
    }
    __syncthreads();

    // ---- K loop: pure ds_read + MFMA (conversion already done at staging)
#pragma unroll
    for (int kt = 0; kt < 8; ++kt) {
        if (kt < 7) {
#pragma unroll
            for (int ct = 0; ct < 4; ++ct) {
                const size_t off = (size_t)(w * 64 + ct * 16 + col) * DD + (kt + 1) * 32 + quad * 8;
                bh1[ct] = *(const s16x8*)(OmH + off);
                bl1[ct] = *(const s16x8*)(OmL + off);
            }
        }
#pragma unroll
        for (int t = 0; t < 2; ++t) {
            const s16x8 ah = *(const s16x8*)&AhS[t * 16 + col][kt * 32 + quad * 8];
            const s16x8 al = *(const s16x8*)&AlS[t * 16 + col][kt * 32 + quad * 8];
#pragma unroll
            for (int ct = 0; ct < 4; ++ct) {
                acc[t][ct] = MFMA16(ah, bh0[ct], acc[t][ct]);
                acc[t][ct] = MFMA16(ah, bl0[ct], acc[t][ct]);
                acc[t][ct] = MFMA16(al, bh0[ct], acc[t][ct]);
            }
        }
#pragma unroll
        for (int ct = 0; ct < 4; ++ct) { bh0[ct] = bh1[ct]; bl0[ct] = bl1[ct]; }
    }

    // ---- row max over 256 cols (red aliases AhS: barrier first)
    __syncthreads();
#pragma unroll
    for (int t = 0; t < 2; ++t)
#pragma unroll
        for (int r = 0; r < 4; ++r) {
            float m = acc[t][0][r];
#pragma unroll
            for (int ct = 1; ct < 4; ++ct) m = fmaxf(m, acc[t][ct][r]);
            red[t * 16 + quad * 4 + r][w * 16 + col] = m;
        }
    __syncthreads();
    {   // parallel reduce: 8 lanes per row + shfl tree
        const int row = tid >> 3, seg = tid & 7;
        float m = red[row][seg * 8];
#pragma unroll
        for (int j = 1; j < 8; ++j) m = fmaxf(m, red[row][seg * 8 + j]);
        m = fmaxf(m, __shfl_xor(m, 1));
        m = fmaxf(m, __shfl_xor(m, 2));
        m = fmaxf(m, __shfl_xor(m, 4));
        if (seg == 0) rowmax_s[row] = m;
    }
    __syncthreads();

    // ---- exp epilogue -> P[n][m] bf16 (P aliases AlS: dead)
#pragma unroll
    for (int t = 0; t < 2; ++t)
#pragma unroll
        for (int r = 0; r < 4; ++r) {
            const int n = t * 16 + quad * 4 + r;
            const float rm = rowmax_s[n];
#pragma unroll
            for (int ct = 0; ct < 4; ++ct) {
                const float val = __expf(acc[t][ct][r] - rm) * 0.0625f;
                const unsigned u = (unsigned)f2bf(val);
                const unsigned up = (unsigned)__shfl_xor((int)u, 1);
                if ((col & 1) == 0)
                    P32[n * 132 + w * 32 + ct * 8 + (col >> 1)] = u | (up << 16);
            }
        }
    __syncthreads();

    // ---- Phi row-major vectorized stores (32 rows)
    {
        const int t7 = tid & 7;
        const int nb = tid >> 3;   // 0..31 = row
#pragma unroll
        for (int s = 0; s < 4; ++s)
            *(uint4*)(Phi + (r0 + nb) * MM + t7 * 8 + s * 64) =
                *(const uint4*)&P[nb][t7 * 8 + s * 64];
    }

    if (kpath) {
        const int b = id >> 7;              // 128 blocks per batch
        const int c = (id >> 3) & 15;       // 8 blocks per 256-row chunk
        const int n0 = (id & 127) * 32;     // row offset within batch
        const int m0 = tid & 31;
        const int nsub = tid >> 5;          // 0..7
#pragma unroll
        for (int mi = 0; mi < 8; ++mi) {
            const int m = mi * 32 + m0;
            unsigned short u[4];
#pragma unroll
            for (int j = 0; j < 4; ++j) u[j] = P[nsub * 4 + j][m];
            *(uint2*)(PhiT + ((size_t)b * MM + m) * NN + n0 + nsub * 4) = *(uint2*)u;
        }
        float z = 0.f;
#pragma unroll
        for (int n = 0; n < 32; ++n) z += bf2f(P[n][tid]);
        atomicAdd(&Zp[((b * NC + c) << 8) + tid], z);
    }
}

// ---------------------------------------------------------------------------
// T1: V fp32 [B*N][256] -> VT bf16 [B][256][N]
// ---------------------------------------------------------------------------
__global__ __launch_bounds__(256) void transpose_v(
    const float* __restrict__ V, unsigned short* __restrict__ VT)
{
    const int tid = threadIdx.x;
    const int ct = blockIdx.x & 3;
    const long r0 = (long)(blockIdx.x >> 2) * 64;
    const int b = (int)(r0 >> 12);
    const int n0 = (int)(r0 & (NN - 1));
    __shared__ unsigned short T[64][72];
    const int rr = tid >> 4, cs = tid & 15;
#pragma unroll
    for (int p = 0; p < 4; ++p) {
        const int r = p * 16 + rr;
        const float4 v = *(const float4*)(V + (r0 + r) * DV + ct * 64 + cs * 4);
        T[cs * 4 + 0][r] = f2bf(v.x); T[cs * 4 + 1][r] = f2bf(v.y);
        T[cs * 4 + 2][r] = f2bf(v.z); T[cs * 4 + 3][r] = f2bf(v.w);
    }
    __syncthreads();
    const int cl = tid >> 3, ns = tid & 7;
#pragma unroll
    for (int p = 0; p < 2; ++p) {
        const int c = p * 32 + cl;
        *(uint4*)(VT + ((size_t)b * DV + ct * 64 + c) * NN + n0 + ns * 8) = *(uint4*)&T[c][ns * 8];
    }
}

// ---------------------------------------------------------------------------
// K2: per-chunk ST_c[dv][m] = sum_kr V[kr][dv]*phi_k[kr][m]  (bf16 MFMA)
// depth-2 register dbuf, XCD-grouped grid (q = hi bits), 3 waves/EU.
// ---------------------------------------------------------------------------
__global__ __launch_bounds__(256, 3) void state_mfma(
    const unsigned short* __restrict__ VT, const unsigned short* __restrict__ PkT,
    unsigned short* __restrict__ ST)
{
    const int tid = threadIdx.x;
    const int w = tid >> 6;
    const int lane = tid & 63;
    const int col = lane & 15, quad = lane >> 4;
    const int q  = blockIdx.x >> 7;
    const int bc = blockIdx.x & 127;
    const int c  = bc & 15;
    const int b  = bc >> 4;
    const int dv0 = (q & 1) * 128 + (w & 1) * 64;
    const int m0  = (q >> 1) * 128 + (w >> 1) * 64;
    const unsigned short* Ab = VT  + (size_t)b * DV * NN + (size_t)c * CHUNK;
    const unsigned short* Bb = PkT + (size_t)b * MM * NN + (size_t)c * CHUNK;

    f32x4 acc[4][4] = {};
    s16x8 a0[4], b0[4], a1[4], b1[4];
#pragma unroll
    for (int t = 0; t < 4; ++t) {
        a0[t] = *(const s16x8*)(Ab + (size_t)(dv0 + t * 16 + col) * NN + quad * 8);
        b0[t] = *(const s16x8*)(Bb + (size_t)(m0 + t * 16 + col) * NN + quad * 8);
    }
#pragma unroll
    for (int kt = 0; kt < 8; ++kt) {
        if (kt < 7) {
#pragma unroll
            for (int t = 0; t < 4; ++t) {
                a1[t] = *(const s16x8*)(Ab + (size_t)(dv0 + t * 16 + col) * NN + (kt + 1) * 32 + quad * 8);
                b1[t] = *(const s16x8*)(Bb + (size_t)(m0 + t * 16 + col) * NN + (kt + 1) * 32 + quad * 8);
            }
        }
#pragma unroll
        for (int i = 0; i < 4; ++i)
#pragma unroll
            for (int j = 0; j < 4; ++j) acc[i][j] = MFMA16(a0[i], b0[j], acc[i][j]);
#pragma unroll
        for (int t = 0; t < 4; ++t) { a0[t] = a1[t]; b0[t] = b1[t]; }
    }
    unsigned short* Sb = ST + (((size_t)(b * NC + c)) << 16);
#pragma unroll
    for (int i = 0; i < 4; ++i)
#pragma unroll
        for (int j = 0; j < 4; ++j)
#pragma unroll
            for (int r = 0; r < 4; ++r)
                Sb[(dv0 + i * 16 + quad * 4 + r) * MM + m0 + j * 16 + col] = f2bf(acc[i][j][r]);
}

// ---------------------------------------------------------------------------
// K3: in-place exclusive prefix over chunks: ST (bf16), Z (fp32)
// ---------------------------------------------------------------------------
__global__ __launch_bounds__(256) void prefix2(
    unsigned short* __restrict__ ST, float* __restrict__ Z)
{
    const long idx = (long)blockIdx.x * 256 + threadIdx.x;
    const int b = (int)(idx >> 16);
    const int r = (int)(idx & 65535);
    float run = 0.f;
#pragma unroll
    for (int c = 0; c < NC; ++c) {
        const size_t off = (((size_t)(b * NC + c)) << 16) + r;
        const float v = bf2f(ST[off]);
        ST[off] = f2bf(run);
        run += v;
    }
    if (idx < BN * MM) {
        const int b2 = (int)(idx >> 8);
        const int m = (int)(idx & 255);
        float rz = 0.f;
#pragma unroll
        for (int c = 0; c < NC; ++c) {
            const size_t off = (size_t)(b2 * NC + c) * MM + m;
            const float v = Z[off];
            Z[off] = rz;
            rz += v;
        }
    }
}

// ---------------------------------------------------------------------------
// K4: Q tile in LDS (staged once); batched/pipelined global frag loads.
// out = (intra causal A@V + phi_q@S_pre) / (rowsum(A) + phi_q.z_pre)
// ---------------------------------------------------------------------------
__global__ __launch_bounds__(256) void out_mfma(
    const unsigned short* __restrict__ PhiQ, const unsigned short* __restrict__ PhiK,
    const unsigned short* __restrict__ VT, const unsigned short* __restrict__ ST,
    const float* __restrict__ Z, float* __restrict__ Out)
{
    const int tid = threadIdx.x;
    const int w = tid >> 6;
    const int lane = tid & 63;
    const int col = lane & 15, quad = lane >> 4;
    const int it = 3 - (blockIdx.x >> 7);
    const int low = blockIdx.x & 127;
    const int c  = low & 15;
    const int b  = low >> 4;
    const size_t chunk_row = (size_t)b * NN + (size_t)c * CHUNK;
    const unsigned short* Qrow = PhiQ + (chunk_row + it * 64) * MM;

    __shared__ unsigned short Qs[64][264];
    __shared__ unsigned short A_s[64][72];
    __shared__ float red[64][68];
    __shared__ float z_s[256];
    __shared__ float den_s[64];

    const float zval = Z[((size_t)(b * NC + c) << 8) + tid];
    s16x8 bk0[8], bk1[8];
#pragma unroll
    for (int ms = 0; ms < 8; ++ms)
        bk0[ms] = *(const s16x8*)(PhiK + (chunk_row)*MM + (size_t)(w * 16 + col) * MM + ms * 32 + quad * 8);
    uint4 qv[8];
#pragma unroll
    for (int i = 0; i < 8; ++i)
        qv[i] = *((const uint4*)Qrow + i * 256 + tid);
    z_s[tid] = zval;
#pragma unroll
    for (int i = 0; i < 8; ++i) {
        const int f = i * 256 + tid;
        *(uint4*)&Qs[f >> 5][(f & 31) * 8] = qv[i];
    }
    __syncthreads();

    f32x4 oacc[4][4] = {};
    float rsum[4][4] = {};

    for (int jt = 0; jt <= it; ++jt) {
        s16x8 bv[8];
        const unsigned short* Vbase = VT + ((size_t)b * DV + w * 64) * NN + (size_t)c * CHUNK + jt * 64;
#pragma unroll
        for (int ks2 = 0; ks2 < 2; ++ks2)
#pragma unroll
            for (int t2 = 0; t2 < 4; ++t2)
                bv[ks2 * 4 + t2] = *(const s16x8*)(Vbase + (size_t)(t2 * 16 + col) * NN + ks2 * 32 + quad * 8);
        f32x4 accA[4] = {};
#pragma unroll
        for (int ms = 0; ms < 8; ++ms)
#pragma unroll
            for (int t = 0; t < 4; ++t) {
                const s16x8 aq = *(const s16x8*)&Qs[t * 16 + col][ms * 32 + quad * 8];
                accA[t] = MFMA16(aq, bk0[ms], accA[t]);
            }
        if (jt < it) {
            const unsigned short* Krn = PhiK + (chunk_row + (jt + 1) * 64) * MM;
#pragma unroll
            for (int ms = 0; ms < 8; ++ms)
                bk1[ms] = *(const s16x8*)(Krn + (size_t)(w * 16 + col) * MM + ms * 32 + quad * 8);
        }
        __syncthreads();
#pragma unroll
        for (int t = 0; t < 4; ++t)
#pragma unroll
            for (int r = 0; r < 4; ++r) {
                const int i_loc = t * 16 + quad * 4 + r;
                const int j_loc = w * 16 + col;
                float v = (jt * 64 + j_loc <= it * 64 + i_loc) ? accA[t][r] : 0.f;
                rsum[t][r] += v;
                A_s[i_loc][j_loc] = f2bf(v);
            }
        __syncthreads();
#pragma unroll
        for (int ks2 = 0; ks2 < 2; ++ks2) {
            s16x8 av[4];
#pragma unroll
            for (int t = 0; t < 4; ++t)
                av[t] = *(const s16x8*)&A_s[t * 16 + col][ks2 * 32 + quad * 8];
#pragma unroll
            for (int t2 = 0; t2 < 4; ++t2)
#pragma unroll
                for (int t = 0; t < 4; ++t)
                    oacc[t][t2] = MFMA16(av[t], bv[ks2 * 4 + t2], oacc[t][t2]);
        }
#pragma unroll
        for (int ms = 0; ms < 8; ++ms) bk0[ms] = bk1[ms];
    }
#pragma unroll
    for (int t = 0; t < 4; ++t)
#pragma unroll
        for (int r = 0; r < 4; ++r)
            red[t * 16 + quad * 4 + r][w * 16 + col] = rsum[t][r];

    const unsigned short* Sb = ST + (((size_t)(b * NC + c)) << 16) + (size_t)(w * 64) * MM;
    s16x8 bs0[4], bs1[4];
#pragma unroll
    for (int t2 = 0; t2 < 4; ++t2)
        bs0[t2] = *(const s16x8*)(Sb + (size_t)(t2 * 16 + col) * MM + quad * 8);
#pragma unroll
    for (int ms = 0; ms < 8; ++ms) {
        if (ms < 7) {
#pragma unroll
            for (int t2 = 0; t2 < 4; ++t2)
                bs1[t2] = *(const s16x8*)(Sb + (size_t)(t2 * 16 + col) * MM + (ms + 1) * 32 + quad * 8);
        }
        s16x8 aq[4];
#pragma unroll
        for (int t = 0; t < 4; ++t)
            aq[t] = *(const s16x8*)&Qs[t * 16 + col][ms * 32 + quad * 8];
#pragma unroll
        for (int t2 = 0; t2 < 4; ++t2)
#pragma unroll
            for (int t = 0; t < 4; ++t)
                oacc[t][t2] = MFMA16(aq[t], bs0[t2], oacc[t][t2]);
#pragma unroll
        for (int t2 = 0; t2 < 4; ++t2) bs0[t2] = bs1[t2];
    }
    {
        const int i = tid & 63;
        const int seg = tid >> 6;
        float d = 0.f;
#pragma unroll
        for (int g = 0; g < 8; ++g) {
            const s16x8 qv8 = *(const s16x8*)&Qs[i][seg * 64 + g * 8];
#pragma unroll
            for (int x = 0; x < 8; ++x)
                d = fmaf(bf2f((unsigned short)qv8[x]), z_s[seg * 64 + g * 8 + x], d);
        }
        red[i][64 + seg] = d;
    }
    __syncthreads();
    if (tid < 64) {
        float s = 0.f;
#pragma unroll
        for (int j = 0; j < 68; ++j) s += red[tid][j];
        den_s[tid] = fmaxf(s, 1e-6f);
    }
    __syncthreads();
#pragma unroll
    for (int t = 0; t < 4; ++t)
#pragma unroll
        for (int r = 0; r < 4; ++r) {
            const int i_loc = t * 16 + quad * 4 + r;
            const float invd = 1.0f / den_s[i_loc];
#pragma unroll
            for (int t2 = 0; t2 < 4; ++t2)
                Out[(chunk_row + it * 64 + i_loc) * DV + w * 64 + t2 * 16 + col] = oacc[t][t2][r] * invd;
        }
}

extern "C" void kernel_launch(void* const* d_in, const int* in_sizes, int n_in,
                              void* d_out, int out_size, void* d_ws, size_t ws_size,
                              hipStream_t stream)
{
    const float* Q  = (const float*)d_in[0];
    const float* K  = (const float*)d_in[1];
    const float* V  = (const float*)d_in[2];
    const float* Om = (const float*)d_in[3];
    float* out = (float*)d_out;

    const size_t NM = (size_t)BN * NN * MM;
    unsigned short* PhiQ  = (unsigned short*)d_ws;
    unsigned short* PhiK  = PhiQ + NM;
    unsigned short* PhiKT = PhiK + NM;
    unsigned short* VT    = PhiKT + NM;
    unsigned short* ST    = VT + NM;
    unsigned short* OmH   = ST + (size_t)BN * NC * DV * MM;
    unsigned short* OmL   = OmH + (size_t)MM * DD;
    float* Z = (float*)(OmL + (size_t)MM * DD);

    hipMemsetAsync(Z, 0, (size_t)BN * NC * MM * sizeof(float), stream);
    omconv<<<dim3(64), dim3(256), 0, stream>>>(Om, OmH, OmL);
    phi_fused<<<dim3(2048), dim3(256), 0, stream>>>(Q, K, OmH, OmL, PhiQ, PhiK, PhiKT, Z);
    transpose_v<<<dim3((BN * NN) / 64 * 4), dim3(256), 0, stream>>>(V, VT);
    state_mfma<<<dim3(BN * NC * 4), dim3(256), 0, stream>>>(VT, PhiKT, ST);
    prefix2<<<dim3((BN * DV * MM) / 256), dim3(256), 0, stream>>>(ST, Z);
    out_mfma<<<dim3(BN * NC * 4), dim3(256), 0, stream>>>(PhiQ, PhiK, VT, ST, Z, out);
}

// Round 3
// 230.668 us; speedup vs baseline: 1.1565x; 1.1565x over previous
//
#include <hip/hip_runtime.h>

#define BN 8
#define NN 4096
#define DD 256   // D_FULL
#define MM 256   // num features
#define DV 256   // value dim
#define CHUNK 256
#define NC (NN / CHUNK)   // 16 chunks per batch

using f32x4 = __attribute__((ext_vector_type(4))) float;
using s16x8 = __attribute__((ext_vector_type(8))) short;

#define MFMA16(a, b, c) __builtin_amdgcn_mfma_f32_16x16x32_bf16(a, b, c, 0, 0, 0)

__device__ __forceinline__ unsigned short f2bf(float x) {
    union { float f; unsigned int u; } v; v.f = x;
    unsigned int r = v.u + 0x7FFF + ((v.u >> 16) & 1);   // RNE
    return (unsigned short)(r >> 16);
}
__device__ __forceinline__ float bf2f(unsigned short u) {
    union { unsigned int u; float f; } v; v.u = ((unsigned int)u) << 16;
    return v.f;
}

// fp32 -> (hi: truncated bf16, lo: RNE bf16 of remainder); hi+lo ~ 2^-17 rel err
__device__ __forceinline__ void split4(const float4 x, unsigned short h[4], unsigned short l[4])
{
    const float xs[4] = {x.x, x.y, x.z, x.w};
#pragma unroll
    for (int j = 0; j < 4; ++j) {
        union { float f; unsigned u; } v; v.f = xs[j];
        const unsigned hm = v.u & 0xFFFF0000u;
        union { unsigned u; float f; } hv; hv.u = hm;
        h[j] = (unsigned short)(hm >> 16);
        l[j] = f2bf(xs[j] - hv.f);
    }
}

// ---------------------------------------------------------------------------
// K0: omega fp32 [256][256] -> hi/lo bf16 in MFMA FRAGMENT ORDER:
// packed[(((w*8+kt)*4+ct)*64 + lane)*8 + e] = Om[w*64+ct*16+(lane&15)][kt*32+(lane>>4)*8+e]
// so each B-frag load in phi_fused is one fully-coalesced 1KB wave-load.
// ---------------------------------------------------------------------------
__global__ __launch_bounds__(256) void omconv(
    const float* __restrict__ Om, unsigned short* __restrict__ OmH,
    unsigned short* __restrict__ OmL)
{
    const int i = blockIdx.x * 256 + threadIdx.x;   // 16384 threads, 4 els each
    const int row = i >> 6;          // 64 threads per 256-col row
    const int k0  = (i & 63) * 4;
    const float4 v = *(const float4*)(Om + (size_t)row * DD + k0);
    const int wv = row >> 6, ct = (row >> 4) & 3, colL = row & 15;
    const int kt = k0 >> 5, quad = (k0 >> 3) & 3, e0 = k0 & 7;
    const int lanep = quad * 16 + colL;
    const size_t off = ((size_t)((wv * 8 + kt) * 4 + ct) * 64 + lanep) * 8 + e0;
    unsigned short h[4], l[4];
    split4(v, h, l);
    *(uint2*)(OmH + off) = *(uint2*)h;
    *(uint2*)(OmL + off) = *(uint2*)l;
}

// ---------------------------------------------------------------------------
// K1 (fused Q+K): phi = exp(X@Om^T - rowmax)/16 via bf16 MFMA hi/lo (3 terms).
// v5: transaction-count attack.
//  - Om B-frags loaded from packed fragment-order layout: 1 ideal 1KB load
//    per (kt,ct) instead of 16 scattered 512B-strided lines.
//  - stage: one full X row per load instr (lane*16B, fully covered lines),
//    split once, 8B ds_writes (2-way bank = free).
//  - PhiT store: 4-lanes-per-m, full 64B lines (16 lines/instr, no partials).
// Blocks 0..1023 = K path (also writes PhiT + per-chunk Z); 1024..2047 = Q.
// ---------------------------------------------------------------------------
__global__ __launch_bounds__(256, 4) void phi_fused(
    const float* __restrict__ Qp, const float* __restrict__ Kp,
    const unsigned short* __restrict__ OmH, const unsigned short* __restrict__ OmL,
    unsigned short* __restrict__ PhiQ, unsigned short* __restrict__ PhiK,
    unsigned short* __restrict__ PhiT, float* __restrict__ Zp)
{
    const int tid = threadIdx.x;
    const int w = tid >> 6;
    const int lane = tid & 63;
    const int col = lane & 15, quad = lane >> 4;
    const bool kpath = blockIdx.x < 1024;
    const int id = kpath ? blockIdx.x : (blockIdx.x - 1024);
    const float* __restrict__ X = kpath ? Kp : Qp;
    unsigned short* __restrict__ Phi = kpath ? PhiK : PhiQ;
    const long r0 = (long)id * 32;

    __shared__ __align__(16) short AhS[32][264];   // 16896 B  (pitch 264 shorts)
    __shared__ __align__(16) short AlS[32][264];   // 16896 B
    __shared__ float rowmax_s[32];
    float (*red)[68] = (float(*)[68])AhS;                     // epilogue alias (Ah dead)
    unsigned short (*P)[264] = (unsigned short(*)[264])AlS;   // epilogue alias (Al dead)
    unsigned int* P32 = (unsigned int*)AlS;

    // ---- stage: each wave loads its 8 rows, one full coalesced row per instr
    {
        float4 xv[8];
#pragma unroll
        for (int j = 0; j < 8; ++j) {
            const int row = w * 8 + j;
            xv[j] = *(const float4*)(X + (r0 + row) * DD + lane * 4);
        }
#pragma unroll
        for (int j = 0; j < 8; ++j) {
            const int row = w * 8 + j;
            unsigned short h[4], l[4];
            split4(xv[j], h, l);
            *(uint2*)&AhS[row][lane * 4] = *(uint2*)h;
            *(uint2*)&AlS[row][lane * 4] = *(uint2*)l;
        }
    }

    // ---- B-frag prefetch for kt=0 (packed layout: per-wave contiguous)
    const unsigned short* OmHw = OmH + (size_t)w * 8 * 4 * 512;
    const unsigned short* OmLw = OmL + (size_t)w * 8 * 4 * 512;
    f32x4 acc[2][4] = {};
    s16x8 bh0[4], bl0[4], bh1[4], bl1[4];
#pragma unroll
    for (int ct = 0; ct < 4; ++ct) {
        const size_t off = ((size_t)ct * 64 + lane) * 8;
        bh0[ct] = *(const s16x8*)(OmHw + off);
        bl0[ct] = *(const s16x8*)(OmLw + off);
    }
    __syncthreads();

    // ---- K loop: pure ds_read + MFMA, dbuf'd ideal Om loads
#pragma unroll
    for (int kt = 0; kt < 8; ++kt) {
        if (kt < 7) {
#pragma unroll
            for (int ct = 0; ct < 4; ++ct) {
                const size_t off = ((size_t)((kt + 1) * 4 + ct) * 64 + lane) * 8;
                bh1[ct] = *(const s16x8*)(OmHw + off);
                bl1[ct] = *(const s16x8*)(OmLw + off);
            }
        }
#pragma unroll
        for (int t = 0; t < 2; ++t) {
            const s16x8 ah = *(const s16x8*)&AhS[t * 16 + col][kt * 32 + quad * 8];
            const s16x8 al = *(const s16x8*)&AlS[t * 16 + col][kt * 32 + quad * 8];
#pragma unroll
            for (int ct = 0; ct < 4; ++ct) {
                acc[t][ct] = MFMA16(ah, bh0[ct], acc[t][ct]);
                acc[t][ct] = MFMA16(ah, bl0[ct], acc[t][ct]);
                acc[t][ct] = MFMA16(al, bh0[ct], acc[t][ct]);
            }
        }
#pragma unroll
        for (int ct = 0; ct < 4; ++ct) { bh0[ct] = bh1[ct]; bl0[ct] = bl1[ct]; }
    }

    // ---- row max over 256 cols (red aliases AhS: barrier first)
    __syncthreads();
#pragma unroll
    for (int t = 0; t < 2; ++t)
#pragma unroll
        for (int r = 0; r < 4; ++r) {
            float m = acc[t][0][r];
#pragma unroll
            for (int ct = 1; ct < 4; ++ct) m = fmaxf(m, acc[t][ct][r]);
            red[t * 16 + quad * 4 + r][w * 16 + col] = m;
        }
    __syncthreads();
    {   // parallel reduce: 8 lanes per row + shfl tree
        const int row = tid >> 3, seg = tid & 7;
        float m = red[row][seg * 8];
#pragma unroll
        for (int j = 1; j < 8; ++j) m = fmaxf(m, red[row][seg * 8 + j]);
        m = fmaxf(m, __shfl_xor(m, 1));
        m = fmaxf(m, __shfl_xor(m, 2));
        m = fmaxf(m, __shfl_xor(m, 4));
        if (seg == 0) rowmax_s[row] = m;
    }
    __syncthreads();

    // ---- exp epilogue -> P[n][m] bf16 (P aliases AlS: dead)
#pragma unroll
    for (int t = 0; t < 2; ++t)
#pragma unroll
        for (int r = 0; r < 4; ++r) {
            const int n = t * 16 + quad * 4 + r;
            const float rm = rowmax_s[n];
#pragma unroll
            for (int ct = 0; ct < 4; ++ct) {
                const float val = __expf(acc[t][ct][r] - rm) * 0.0625f;
                const unsigned u = (unsigned)f2bf(val);
                const unsigned up = (unsigned)__shfl_xor((int)u, 1);
                if ((col & 1) == 0)
                    P32[n * 132 + w * 32 + ct * 8 + (col >> 1)] = u | (up << 16);
            }
        }
    __syncthreads();

    // ---- Phi row-major vectorized stores (32 rows)
    {
        const int t7 = tid & 7;
        const int nb = tid >> 3;   // 0..31 = row
#pragma unroll
        for (int s = 0; s < 4; ++s)
            *(uint4*)(Phi + (r0 + nb) * MM + t7 * 8 + s * 64) =
                *(const uint4*)&P[nb][t7 * 8 + s * 64];
    }

    if (kpath) {
        const int b = id >> 7;              // 128 blocks per batch
        const int c = (id >> 3) & 15;       // 8 blocks per 256-row chunk
        const int n0 = (id & 127) * 32;     // row offset within batch
        // PhiT: thread -> (m = mi*64 + tid>>2, n-chunk = (tid&3)*8), full 64B lines
        const int nb4 = (tid & 3) * 8;
        const int mBase = tid >> 2;         // 0..63
#pragma unroll
        for (int mi = 0; mi < 4; ++mi) {
            const int m = mi * 64 + mBase;
            unsigned short u[8];
#pragma unroll
            for (int j = 0; j < 8; ++j) u[j] = P[nb4 + j][m];
            *(uint4*)(PhiT + ((size_t)b * MM + m) * NN + n0 + nb4) = *(uint4*)u;
        }
        float z = 0.f;
#pragma unroll
        for (int n = 0; n < 32; ++n) z += bf2f(P[n][tid]);
        atomicAdd(&Zp[((b * NC + c) << 8) + tid], z);
    }
}

// ---------------------------------------------------------------------------
// T1: V fp32 [B*N][256] -> VT bf16 [B][256][N]
// ---------------------------------------------------------------------------
__global__ __launch_bounds__(256) void transpose_v(
    const float* __restrict__ V, unsigned short* __restrict__ VT)
{
    const int tid = threadIdx.x;
    const int ct = blockIdx.x & 3;
    const long r0 = (long)(blockIdx.x >> 2) * 64;
    const int b = (int)(r0 >> 12);
    const int n0 = (int)(r0 & (NN - 1));
    __shared__ unsigned short T[64][72];
    const int rr = tid >> 4, cs = tid & 15;
#pragma unroll
    for (int p = 0; p < 4; ++p) {
        const int r = p * 16 + rr;
        const float4 v = *(const float4*)(V + (r0 + r) * DV + ct * 64 + cs * 4);
        T[cs * 4 + 0][r] = f2bf(v.x); T[cs * 4 + 1][r] = f2bf(v.y);
        T[cs * 4 + 2][r] = f2bf(v.z); T[cs * 4 + 3][r] = f2bf(v.w);
    }
    __syncthreads();
    const int cl = tid >> 3, ns = tid & 7;
#pragma unroll
    for (int p = 0; p < 2; ++p) {
        const int c = p * 32 + cl;
        *(uint4*)(VT + ((size_t)b * DV + ct * 64 + c) * NN + n0 + ns * 8) = *(uint4*)&T[c][ns * 8];
    }
}

// ---------------------------------------------------------------------------
// K2: per-chunk ST_c[dv][m] = sum_kr V[kr][dv]*phi_k[kr][m]  (bf16 MFMA)
// depth-2 register dbuf, XCD-grouped grid (q = hi bits), 3 waves/EU.
// ---------------------------------------------------------------------------
__global__ __launch_bounds__(256, 3) void state_mfma(
    const unsigned short* __restrict__ VT, const unsigned short* __restrict__ PkT,
    unsigned short* __restrict__ ST)
{
    const int tid = threadIdx.x;
    const int w = tid >> 6;
    const int lane = tid & 63;
    const int col = lane & 15, quad = lane >> 4;
    const int q  = blockIdx.x >> 7;
    const int bc = blockIdx.x & 127;
    const int c  = bc & 15;
    const int b  = bc >> 4;
    const int dv0 = (q & 1) * 128 + (w & 1) * 64;
    const int m0  = (q >> 1) * 128 + (w >> 1) * 64;
    const unsigned short* Ab = VT  + (size_t)b * DV * NN + (size_t)c * CHUNK;
    const unsigned short* Bb = PkT + (size_t)b * MM * NN + (size_t)c * CHUNK;

    f32x4 acc[4][4] = {};
    s16x8 a0[4], b0[4], a1[4], b1[4];
#pragma unroll
    for (int t = 0; t < 4; ++t) {
        a0[t] = *(const s16x8*)(Ab + (size_t)(dv0 + t * 16 + col) * NN + quad * 8);
        b0[t] = *(const s16x8*)(Bb + (size_t)(m0 + t * 16 + col) * NN + quad * 8);
    }
#pragma unroll
    for (int kt = 0; kt < 8; ++kt) {
        if (kt < 7) {
#pragma unroll
            for (int t = 0; t < 4; ++t) {
                a1[t] = *(const s16x8*)(Ab + (size_t)(dv0 + t * 16 + col) * NN + (kt + 1) * 32 + quad * 8);
                b1[t] = *(const s16x8*)(Bb + (size_t)(m0 + t * 16 + col) * NN + (kt + 1) * 32 + quad * 8);
            }
        }
#pragma unroll
        for (int i = 0; i < 4; ++i)
#pragma unroll
            for (int j = 0; j < 4; ++j) acc[i][j] = MFMA16(a0[i], b0[j], acc[i][j]);
#pragma unroll
        for (int t = 0; t < 4; ++t) { a0[t] = a1[t]; b0[t] = b1[t]; }
    }
    unsigned short* Sb = ST + (((size_t)(b * NC + c)) << 16);
#pragma unroll
    for (int i = 0; i < 4; ++i)
#pragma unroll
        for (int j = 0; j < 4; ++j)
#pragma unroll
            for (int r = 0; r < 4; ++r)
                Sb[(dv0 + i * 16 + quad * 4 + r) * MM + m0 + j * 16 + col] = f2bf(acc[i][j][r]);
}

// ---------------------------------------------------------------------------
// K3: in-place exclusive prefix over chunks: ST (bf16), Z (fp32)
// ---------------------------------------------------------------------------
__global__ __launch_bounds__(256) void prefix2(
    unsigned short* __restrict__ ST, float* __restrict__ Z)
{
    const long idx = (long)blockIdx.x * 256 + threadIdx.x;
    const int b = (int)(idx >> 16);
    const int r = (int)(idx & 65535);
    float run = 0.f;
#pragma unroll
    for (int c = 0; c < NC; ++c) {
        const size_t off = (((size_t)(b * NC + c)) << 16) + r;
        const float v = bf2f(ST[off]);
        ST[off] = f2bf(run);
        run += v;
    }
    if (idx < BN * MM) {
        const int b2 = (int)(idx >> 8);
        const int m = (int)(idx & 255);
        float rz = 0.f;
#pragma unroll
        for (int c = 0; c < NC; ++c) {
            const size_t off = (size_t)(b2 * NC + c) * MM + m;
            const float v = Z[off];
            Z[off] = rz;
            rz += v;
        }
    }
}

// ---------------------------------------------------------------------------
// K4: Q tile in LDS (staged once); batched/pipelined global frag loads.
// out = (intra causal A@V + phi_q@S_pre) / (rowsum(A) + phi_q.z_pre)
// ---------------------------------------------------------------------------
__global__ __launch_bounds__(256) void out_mfma(
    const unsigned short* __restrict__ PhiQ, const unsigned short* __restrict__ PhiK,
    const unsigned short* __restrict__ VT, const unsigned short* __restrict__ ST,
    const float* __restrict__ Z, float* __restrict__ Out)
{
    const int tid = threadIdx.x;
    const int w = tid >> 6;
    const int lane = tid & 63;
    const int col = lane & 15, quad = lane >> 4;
    const int it = 3 - (blockIdx.x >> 7);
    const int low = blockIdx.x & 127;
    const int c  = low & 15;
    const int b  = low >> 4;
    const size_t chunk_row = (size_t)b * NN + (size_t)c * CHUNK;
    const unsigned short* Qrow = PhiQ + (chunk_row + it * 64) * MM;

    __shared__ unsigned short Qs[64][264];
    __shared__ unsigned short A_s[64][72];
    __shared__ float red[64][68];
    __shared__ float z_s[256];
    __shared__ float den_s[64];

    const float zval = Z[((size_t)(b * NC + c) << 8) + tid];
    s16x8 bk0[8], bk1[8];
#pragma unroll
    for (int ms = 0; ms < 8; ++ms)
        bk0[ms] = *(const s16x8*)(PhiK + (chunk_row)*MM + (size_t)(w * 16 + col) * MM + ms * 32 + quad * 8);
    uint4 qv[8];
#pragma unroll
    for (int i = 0; i < 8; ++i)
        qv[i] = *((const uint4*)Qrow + i * 256 + tid);
    z_s[tid] = zval;
#pragma unroll
    for (int i = 0; i < 8; ++i) {
        const int f = i * 256 + tid;
        *(uint4*)&Qs[f >> 5][(f & 31) * 8] = qv[i];
    }
    __syncthreads();

    f32x4 oacc[4][4] = {};
    float rsum[4][4] = {};

    for (int jt = 0; jt <= it; ++jt) {
        s16x8 bv[8];
        const unsigned short* Vbase = VT + ((size_t)b * DV + w * 64) * NN + (size_t)c * CHUNK + jt * 64;
#pragma unroll
        for (int ks2 = 0; ks2 < 2; ++ks2)
#pragma unroll
            for (int t2 = 0; t2 < 4; ++t2)
                bv[ks2 * 4 + t2] = *(const s16x8*)(Vbase + (size_t)(t2 * 16 + col) * NN + ks2 * 32 + quad * 8);
        f32x4 accA[4] = {};
#pragma unroll
        for (int ms = 0; ms < 8; ++ms)
#pragma unroll
            for (int t = 0; t < 4; ++t) {
                const s16x8 aq = *(const s16x8*)&Qs[t * 16 + col][ms * 32 + quad * 8];
                accA[t] = MFMA16(aq, bk0[ms], accA[t]);
            }
        if (jt < it) {
            const unsigned short* Krn = PhiK + (chunk_row + (jt + 1) * 64) * MM;
#pragma unroll
            for (int ms = 0; ms < 8; ++ms)
                bk1[ms] = *(const s16x8*)(Krn + (size_t)(w * 16 + col) * MM + ms * 32 + quad * 8);
        }
        __syncthreads();
#pragma unroll
        for (int t = 0; t < 4; ++t)
#pragma unroll
            for (int r = 0; r < 4; ++r) {
                const int i_loc = t * 16 + quad * 4 + r;
                const int j_loc = w * 16 + col;
                float v = (jt * 64 + j_loc <= it * 64 + i_loc) ? accA[t][r] : 0.f;
                rsum[t][r] += v;
                A_s[i_loc][j_loc] = f2bf(v);
            }
        __syncthreads();
#pragma unroll
        for (int ks2 = 0; ks2 < 2; ++ks2) {
            s16x8 av[4];
#pragma unroll
            for (int t = 0; t < 4; ++t)
                av[t] = *(const s16x8*)&A_s[t * 16 + col][ks2 * 32 + quad * 8];
#pragma unroll
            for (int t2 = 0; t2 < 4; ++t2)
#pragma unroll
                for (int t = 0; t < 4; ++t)
                    oacc[t][t2] = MFMA16(av[t], bv[ks2 * 4 + t2], oacc[t][t2]);
        }
#pragma unroll
        for (int ms = 0; ms < 8; ++ms) bk0[ms] = bk1[ms];
    }
#pragma unroll
    for (int t = 0; t < 4; ++t)
#pragma unroll
        for (int r = 0; r < 4; ++r)
            red[t * 16 + quad * 4 + r][w * 16 + col] = rsum[t][r];

    const unsigned short* Sb = ST + (((size_t)(b * NC + c)) << 16) + (size_t)(w * 64) * MM;
    s16x8 bs0[4], bs1[4];
#pragma unroll
    for (int t2 = 0; t2 < 4; ++t2)
        bs0[t2] = *(const s16x8*)(Sb + (size_t)(t2 * 16 + col) * MM + quad * 8);
#pragma unroll
    for (int ms = 0; ms < 8; ++ms) {
        if (ms < 7) {
#pragma unroll
            for (int t2 = 0; t2 < 4; ++t2)
                bs1[t2] = *(const s16x8*)(Sb + (size_t)(t2 * 16 + col) * MM + (ms + 1) * 32 + quad * 8);
        }
        s16x8 aq[4];
#pragma unroll
        for (int t = 0; t < 4; ++t)
            aq[t] = *(const s16x8*)&Qs[t * 16 + col][ms * 32 + quad * 8];
#pragma unroll
        for (int t2 = 0; t2 < 4; ++t2)
#pragma unroll
            for (int t = 0; t < 4; ++t)
                oacc[t][t2] = MFMA16(aq[t], bs0[t2], oacc[t][t2]);
#pragma unroll
        for (int t2 = 0; t2 < 4; ++t2) bs0[t2] = bs1[t2];
    }
    {
        const int i = tid & 63;
        const int seg = tid >> 6;
        float d = 0.f;
#pragma unroll
        for (int g = 0; g < 8; ++g) {
            const s16x8 qv8 = *(const s16x8*)&Qs[i][seg * 64 + g * 8];
#pragma unroll
            for (int x = 0; x < 8; ++x)
                d = fmaf(bf2f((unsigned short)qv8[x]), z_s[seg * 64 + g * 8 + x], d);
        }
        red[i][64 + seg] = d;
    }
    __syncthreads();
    if (tid < 64) {
        float s = 0.f;
#pragma unroll
        for (int j = 0; j < 68; ++j) s += red[tid][j];
        den_s[tid] = fmaxf(s, 1e-6f);
    }
    __syncthreads();
#pragma unroll
    for (int t = 0; t < 4; ++t)
#pragma unroll
        for (int r = 0; r < 4; ++r) {
            const int i_loc = t * 16 + quad * 4 + r;
            const float invd = 1.0f / den_s[i_loc];
#pragma unroll
            for (int t2 = 0; t2 < 4; ++t2)
                Out[(chunk_row + it * 64 + i_loc) * DV + w * 64 + t2 * 16 + col] = oacc[t][t2][r] * invd;
        }
}

extern "C" void kernel_launch(void* const* d_in, const int* in_sizes, int n_in,
                              void* d_out, int out_size, void* d_ws, size_t ws_size,
                              hipStream_t stream)
{
    const float* Q  = (const float*)d_in[0];
    const float* K  = (const float*)d_in[1];
    const float* V  = (const float*)d_in[2];
    const float* Om = (const float*)d_in[3];
    float* out = (float*)d_out;

    const size_t NM = (size_t)BN * NN * MM;
    unsigned short* PhiQ  = (unsigned short*)d_ws;
    unsigned short* PhiK  = PhiQ + NM;
    unsigned short* PhiKT = PhiK + NM;
    unsigned short* VT    = PhiKT + NM;
    unsigned short* ST    = VT + NM;
    unsigned short* OmH   = ST + (size_t)BN * NC * DV * MM;
    unsigned short* OmL   = OmH + (size_t)MM * DD;
    float* Z = (float*)(OmL + (size_t)MM * DD);

    hipMemsetAsync(Z, 0, (size_t)BN * NC * MM * sizeof(float), stream);
    omconv<<<dim3(64), dim3(256), 0, stream>>>(Om, OmH, OmL);
    phi_fused<<<dim3(2048), dim3(256), 0, stream>>>(Q, K, OmH, OmL, PhiQ, PhiK, PhiKT, Z);
    transpose_v<<<dim3((BN * NN) / 64 * 4), dim3(256), 0, stream>>>(V, VT);
    state_mfma<<<dim3(BN * NC * 4), dim3(256), 0, stream>>>(VT, PhiKT, ST);
    prefix2<<<dim3((BN * DV * MM) / 256), dim3(256), 0, stream>>>(ST, Z);
    out_mfma<<<dim3(BN * NC * 4), dim3(256), 0, stream>>>(PhiQ, PhiK, VT, ST, Z, out);
}

// Round 4
// 222.136 us; speedup vs baseline: 1.2010x; 1.0384x over previous
//
#include <hip/hip_runtime.h>

#define BN 8
#define NN 4096
#define DD 256   // D_FULL
#define MM 256   // num features
#define DV 256   // value dim
#define CHUNK 256
#define NC (NN / CHUNK)   // 16 chunks per batch

using f32x4 = __attribute__((ext_vector_type(4))) float;
using s16x8 = __attribute__((ext_vector_type(8))) short;

#define MFMA16(a, b, c) __builtin_amdgcn_mfma_f32_16x16x32_bf16(a, b, c, 0, 0, 0)

// ---------------------------------------------------------------------------
// Fragment-order layouts (per (b,c) chunk, 65536 elements each):
//  PhiTF[(mq*8 + kt)*4 + t][lane][e]  = phiK[n=kt*32+(l>>4)*8+e][m=mq*64+t*16+(l&15)]
//  VTF  [(dvq*8 + kt)*4 + t][lane][e] = V   [n=kt*32+(l>>4)*8+e][dv=dvq*64+t*16+(l&15)]
//  STF  [(dvq*8 + ms)*4 + t2][lane][e]= S   [m=ms*32+(l>>4)*8+e][dv=dvq*64+t2*16+(l&15)]
//  PhiKF[(jt*8 + ms)*4 + w][lane][e]  = phiK[n=jt*64+w*16+(l&15)][m=ms*32+(l>>4)*8+e]
// Every consumer fragment load = one contiguous 1KB wave-load.
// ---------------------------------------------------------------------------

__device__ __forceinline__ unsigned short f2bf(float x) {
    union { float f; unsigned int u; } v; v.f = x;
    unsigned int r = v.u + 0x7FFF + ((v.u >> 16) & 1);   // RNE
    return (unsigned short)(r >> 16);
}
__device__ __forceinline__ float bf2f(unsigned short u) {
    union { unsigned int u; float f; } v; v.u = ((unsigned int)u) << 16;
    return v.f;
}

// fp32 -> (hi: truncated bf16, lo: RNE bf16 of remainder); hi+lo ~ 2^-17 rel err
__device__ __forceinline__ void split4(const float4 x, unsigned short h[4], unsigned short l[4])
{
    const float xs[4] = {x.x, x.y, x.z, x.w};
#pragma unroll
    for (int j = 0; j < 4; ++j) {
        union { float f; unsigned u; } v; v.f = xs[j];
        const unsigned hm = v.u & 0xFFFF0000u;
        union { unsigned u; float f; } hv; hv.u = hm;
        h[j] = (unsigned short)(hm >> 16);
        l[j] = f2bf(xs[j] - hv.f);
    }
}

// ---------------------------------------------------------------------------
// K0: omega fp32 [256][256] -> hi/lo bf16 in MFMA FRAGMENT ORDER
// packed[(((w*8+kt)*4+ct)*64 + lane)*8 + e] = Om[w*64+ct*16+(lane&15)][kt*32+(lane>>4)*8+e]
// ---------------------------------------------------------------------------
__global__ __launch_bounds__(256) void omconv(
    const float* __restrict__ Om, unsigned short* __restrict__ OmH,
    unsigned short* __restrict__ OmL)
{
    const int i = blockIdx.x * 256 + threadIdx.x;   // 16384 threads, 4 els each
    const int row = i >> 6;          // 64 threads per 256-col row
    const int k0  = (i & 63) * 4;
    const float4 v = *(const float4*)(Om + (size_t)row * DD + k0);
    const int wv = row >> 6, ct = (row >> 4) & 3, colL = row & 15;
    const int kt = k0 >> 5, quad = (k0 >> 3) & 3, e0 = k0 & 7;
    const int lanep = quad * 16 + colL;
    const size_t off = ((size_t)((wv * 8 + kt) * 4 + ct) * 64 + lanep) * 8 + e0;
    unsigned short h[4], l[4];
    split4(v, h, l);
    *(uint2*)(OmH + off) = *(uint2*)h;
    *(uint2*)(OmL + off) = *(uint2*)l;
}

// ---------------------------------------------------------------------------
// K1 (fused Q+K): phi = exp(X@Om^T - rowmax)/16 via bf16 MFMA hi/lo (3 terms).
// v6: epilogue writes fragment-order PhiKF + PhiTF (K path) / row-major PhiQ
// (Q path). Core K-loop identical to v5 (packed-Om ideal loads).
// Blocks 0..1023 = K path (also writes Z); 1024..2047 = Q path.
// ---------------------------------------------------------------------------
__global__ __launch_bounds__(256, 4) void phi_fused(
    const float* __restrict__ Qp, const float* __restrict__ Kp,
    const unsigned short* __restrict__ OmH, const unsigned short* __restrict__ OmL,
    unsigned short* __restrict__ PhiQ, unsigned short* __restrict__ PhiKF,
    unsigned short* __restrict__ PhiTF, float* __restrict__ Zp)
{
    const int tid = threadIdx.x;
    const int w = tid >> 6;
    const int lane = tid & 63;
    const int col = lane & 15, quad = lane >> 4;
    const bool kpath = blockIdx.x < 1024;
    const int id = kpath ? blockIdx.x : (blockIdx.x - 1024);
    const float* __restrict__ X = kpath ? Kp : Qp;
    const long r0 = (long)id * 32;

    __shared__ __align__(16) short AhS[32][264];   // 16896 B  (pitch 264 shorts)
    __shared__ __align__(16) short AlS[32][264];   // 16896 B
    __shared__ float rowmax_s[32];
    float (*red)[68] = (float(*)[68])AhS;                     // epilogue alias (Ah dead)
    unsigned short (*P)[264] = (unsigned short(*)[264])AlS;   // epilogue alias (Al dead)
    unsigned int* P32 = (unsigned int*)AlS;

    // ---- stage: each wave loads its 8 rows, one full coalesced row per instr
    {
        float4 xv[8];
#pragma unroll
        for (int j = 0; j < 8; ++j) {
            const int row = w * 8 + j;
            xv[j] = *(const float4*)(X + (r0 + row) * DD + lane * 4);
        }
#pragma unroll
        for (int j = 0; j < 8; ++j) {
            const int row = w * 8 + j;
            unsigned short h[4], l[4];
            split4(xv[j], h, l);
            *(uint2*)&AhS[row][lane * 4] = *(uint2*)h;
            *(uint2*)&AlS[row][lane * 4] = *(uint2*)l;
        }
    }

    // ---- B-frag prefetch for kt=0 (packed layout: per-wave contiguous)
    const unsigned short* OmHw = OmH + (size_t)w * 8 * 4 * 512;
    const unsigned short* OmLw = OmL + (size_t)w * 8 * 4 * 512;
    f32x4 acc[2][4] = {};
    s16x8 bh0[4], bl0[4], bh1[4], bl1[4];
#pragma unroll
    for (int ct = 0; ct < 4; ++ct) {
        const size_t off = ((size_t)ct * 64 + lane) * 8;
        bh0[ct] = *(const s16x8*)(OmHw + off);
        bl0[ct] = *(const s16x8*)(OmLw + off);
    }
    __syncthreads();

    // ---- K loop: pure ds_read + MFMA, dbuf'd ideal Om loads
#pragma unroll
    for (int kt = 0; kt < 8; ++kt) {
        if (kt < 7) {
#pragma unroll
            for (int ct = 0; ct < 4; ++ct) {
                const size_t off = ((size_t)((kt + 1) * 4 + ct) * 64 + lane) * 8;
                bh1[ct] = *(const s16x8*)(OmHw + off);
                bl1[ct] = *(const s16x8*)(OmLw + off);
            }
        }
#pragma unroll
        for (int t = 0; t < 2; ++t) {
            const s16x8 ah = *(const s16x8*)&AhS[t * 16 + col][kt * 32 + quad * 8];
            const s16x8 al = *(const s16x8*)&AlS[t * 16 + col][kt * 32 + quad * 8];
#pragma unroll
            for (int ct = 0; ct < 4; ++ct) {
                acc[t][ct] = MFMA16(ah, bh0[ct], acc[t][ct]);
                acc[t][ct] = MFMA16(ah, bl0[ct], acc[t][ct]);
                acc[t][ct] = MFMA16(al, bh0[ct], acc[t][ct]);
            }
        }
#pragma unroll
        for (int ct = 0; ct < 4; ++ct) { bh0[ct] = bh1[ct]; bl0[ct] = bl1[ct]; }
    }

    // ---- row max over 256 cols (red aliases AhS: barrier first)
    __syncthreads();
#pragma unroll
    for (int t = 0; t < 2; ++t)
#pragma unroll
        for (int r = 0; r < 4; ++r) {
            float m = acc[t][0][r];
#pragma unroll
            for (int ct = 1; ct < 4; ++ct) m = fmaxf(m, acc[t][ct][r]);
            red[t * 16 + quad * 4 + r][w * 16 + col] = m;
        }
    __syncthreads();
    {   // parallel reduce: 8 lanes per row + shfl tree
        const int row = tid >> 3, seg = tid & 7;
        float m = red[row][seg * 8];
#pragma unroll
        for (int j = 1; j < 8; ++j) m = fmaxf(m, red[row][seg * 8 + j]);
        m = fmaxf(m, __shfl_xor(m, 1));
        m = fmaxf(m, __shfl_xor(m, 2));
        m = fmaxf(m, __shfl_xor(m, 4));
        if (seg == 0) rowmax_s[row] = m;
    }
    __syncthreads();

    // ---- exp epilogue -> P[n][m] bf16 (P aliases AlS: dead)
#pragma unroll
    for (int t = 0; t < 2; ++t)
#pragma unroll
        for (int r = 0; r < 4; ++r) {
            const int n = t * 16 + quad * 4 + r;
            const float rm = rowmax_s[n];
#pragma unroll
            for (int ct = 0; ct < 4; ++ct) {
                const float val = __expf(acc[t][ct][r] - rm) * 0.0625f;
                const unsigned u = (unsigned)f2bf(val);
                const unsigned up = (unsigned)__shfl_xor((int)u, 1);
                if ((col & 1) == 0)
                    P32[n * 132 + w * 32 + ct * 8 + (col >> 1)] = u | (up << 16);
            }
        }
    __syncthreads();

    if (!kpath) {
        // ---- PhiQ row-major vectorized stores (32 rows)
        const int t7 = tid & 7;
        const int nb = tid >> 3;   // 0..31 = row
#pragma unroll
        for (int s = 0; s < 4; ++s)
            *(uint4*)(PhiQ + (r0 + nb) * MM + t7 * 8 + s * 64) =
                *(const uint4*)&P[nb][t7 * 8 + s * 64];
    } else {
        const int b = id >> 7;              // 128 blocks per batch
        const int ib = id & 127;
        const int c = ib >> 3;              // 8 blocks per 256-row chunk
        const size_t bc = ((size_t)(b * NC + c)) << 16;
        const int jt = (ib >> 1) & 3;       // 64-row k-group within chunk
        const int half = ib & 1;            // which 32-row half of the jt group
        const int ktp = ib & 7;             // 32-row k-subtile within chunk
        // PhiKF: frag rows = k (jt,w), contraction = m. 16B LDS row-reads.
#pragma unroll
        for (int p = 0; p < 4; ++p) {
            const int msw = p * 4 + (tid >> 6);
            const int ms = msw >> 1, wl = msw & 1;
            const uint4 v = *(const uint4*)&P[wl * 16 + (lane & 15)][ms * 32 + (lane >> 4) * 8];
            *(uint4*)(PhiKF + bc + (((size_t)(jt * 8 + ms) * 4 + half * 2 + wl) * 64 + lane) * 8) = v;
        }
        // PhiTF: frag rows = m (mq,t), contraction = n. column gather.
#pragma unroll
        for (int p = 0; p < 4; ++p) {
            const int mq = p, t = tid >> 6;
            unsigned short u[8];
#pragma unroll
            for (int e = 0; e < 8; ++e)
                u[e] = P[(lane >> 4) * 8 + e][mq * 64 + t * 16 + (lane & 15)];
            *(uint4*)(PhiTF + bc + (((size_t)(mq * 8 + ktp) * 4 + t) * 64 + lane) * 8) = *(uint4*)u;
        }
        float z = 0.f;
#pragma unroll
        for (int n = 0; n < 32; ++n) z += bf2f(P[n][tid]);
        atomicAdd(&Zp[((b * NC + c) << 8) + tid], z);
    }
}

// ---------------------------------------------------------------------------
// T1: V fp32 [B*N][256] -> VTF bf16 fragment order
// block: 64 n-rows (2 kt) x 64 dv (one dvq group)
// ---------------------------------------------------------------------------
__global__ __launch_bounds__(256) void transpose_v(
    const float* __restrict__ V, unsigned short* __restrict__ VTF)
{
    const int tid = threadIdx.x;
    const int ct = blockIdx.x & 3;                 // dvq
    const long r0 = (long)(blockIdx.x >> 2) * 64;
    const int b = (int)(r0 >> 12);
    const int n0 = (int)(r0 & (NN - 1));
    const int c = n0 >> 8;
    const int kt0 = (n0 & 255) >> 5;               // {0,2,4,6}
    const size_t bc = ((size_t)(b * NC + c)) << 16;
    __shared__ unsigned short T[64][72];           // [dv_local][n_local]
    const int rr = tid >> 4, cs = tid & 15;
#pragma unroll
    for (int p = 0; p < 4; ++p) {
        const int r = p * 16 + rr;
        const float4 v = *(const float4*)(V + (r0 + r) * DV + ct * 64 + cs * 4);
        T[cs * 4 + 0][r] = f2bf(v.x); T[cs * 4 + 1][r] = f2bf(v.y);
        T[cs * 4 + 2][r] = f2bf(v.z); T[cs * 4 + 3][r] = f2bf(v.w);
    }
    __syncthreads();
    const int t = (tid >> 6) & 3, lane = tid & 63;
#pragma unroll
    for (int p = 0; p < 2; ++p) {
        const int kt2 = p;
        const uint4 v = *(const uint4*)&T[t * 16 + (lane & 15)][kt2 * 32 + (lane >> 4) * 8];
        *(uint4*)(VTF + bc + (((size_t)(ct * 8 + kt0 + kt2) * 4 + t) * 64 + lane) * 8) = v;
    }
}

// ---------------------------------------------------------------------------
// K2: per-chunk S_c[m][dv] = sum_n phi_k[n][m]*V[n][dv]  (bf16 MFMA)
// All operand loads are ideal 1KB fragment loads; C-write coalesced uint2.
// ---------------------------------------------------------------------------
__global__ __launch_bounds__(256, 3) void state_mfma(
    const unsigned short* __restrict__ VTF, const unsigned short* __restrict__ PhiTF,
    unsigned short* __restrict__ STF)
{
    const int tid = threadIdx.x;
    const int w = tid >> 6;
    const int lane = tid & 63;
    const int col = lane & 15, quad = lane >> 4;
    const int q  = blockIdx.x >> 7;
    const int bci = blockIdx.x & 127;
    const int c  = bci & 15;
    const int b  = bci >> 4;
    const int dvq = (q & 1) * 2 + (w & 1);
    const int mq  = (q >> 1) * 2 + (w >> 1);
    const size_t bc = ((size_t)(b * NC + c)) << 16;
    const unsigned short* Af = VTF   + bc + (size_t)dvq * 16384;
    const unsigned short* Bf = PhiTF + bc + (size_t)mq  * 16384;

    f32x4 acc[4][4] = {};   // [i = m-sub][j = dv-sub]
    s16x8 a0[4], b0[4], a1[4], b1[4];
#pragma unroll
    for (int t = 0; t < 4; ++t) {
        a0[t] = *(const s16x8*)(Af + ((size_t)t * 64 + lane) * 8);
        b0[t] = *(const s16x8*)(Bf + ((size_t)t * 64 + lane) * 8);
    }
#pragma unroll
    for (int kt = 0; kt < 8; ++kt) {
        if (kt < 7) {
#pragma unroll
            for (int t = 0; t < 4; ++t) {
                a1[t] = *(const s16x8*)(Af + ((size_t)((kt + 1) * 4 + t) * 64 + lane) * 8);
                b1[t] = *(const s16x8*)(Bf + ((size_t)((kt + 1) * 4 + t) * 64 + lane) * 8);
            }
        }
#pragma unroll
        for (int i = 0; i < 4; ++i)
#pragma unroll
            for (int j = 0; j < 4; ++j) acc[i][j] = MFMA16(b0[i], a0[j], acc[i][j]);
#pragma unroll
        for (int t = 0; t < 4; ++t) { a0[t] = a1[t]; b0[t] = b1[t]; }
    }
    // C-write: STF element (dvq, ms=mq*2+(i>>1), t2=j, lane', e) — coalesced 8B stores
#pragma unroll
    for (int i = 0; i < 4; ++i)
#pragma unroll
        for (int j = 0; j < 4; ++j) {
            unsigned short s[4];
#pragma unroll
            for (int r = 0; r < 4; ++r) s[r] = f2bf(acc[i][j][r]);
            const int lanep = ((i & 1) * 2 + (quad >> 1)) * 16 + col;
            const size_t off = (((size_t)(dvq * 8 + mq * 2 + (i >> 1)) * 4 + j) * 64 + lanep) * 8 + (quad & 1) * 4;
            *(uint2*)(STF + bc + off) = *(uint2*)s;
        }
}

// ---------------------------------------------------------------------------
// K3: in-place exclusive prefix over chunks: STF (bf16), Z (fp32)
// (layout-agnostic: same element offset across chunk-strided blocks)
// ---------------------------------------------------------------------------
__global__ __launch_bounds__(256) void prefix2(
    unsigned short* __restrict__ ST, float* __restrict__ Z)
{
    const long idx = (long)blockIdx.x * 256 + threadIdx.x;
    const int b = (int)(idx >> 16);
    const int r = (int)(idx & 65535);
    float run = 0.f;
#pragma unroll
    for (int c = 0; c < NC; ++c) {
        const size_t off = (((size_t)(b * NC + c)) << 16) + r;
        const float v = bf2f(ST[off]);
        ST[off] = f2bf(run);
        run += v;
    }
    if (idx < BN * MM) {
        const int b2 = (int)(idx >> 8);
        const int m = (int)(idx & 255);
        float rz = 0.f;
#pragma unroll
        for (int c = 0; c < NC; ++c) {
            const size_t off = (size_t)(b2 * NC + c) * MM + m;
            const float v = Z[off];
            Z[off] = rz;
            rz += v;
        }
    }
}

// ---------------------------------------------------------------------------
// K4: out = (intra causal A@V + phi_q@S_pre) / (rowsum(A) + phi_q.z_pre)
// All global fragment loads (bk/bv/bs) are ideal 1KB wave-loads.
// ---------------------------------------------------------------------------
__global__ __launch_bounds__(256) void out_mfma(
    const unsigned short* __restrict__ PhiQ, const unsigned short* __restrict__ PhiKF,
    const unsigned short* __restrict__ VTF, const unsigned short* __restrict__ STF,
    const float* __restrict__ Z, float* __restrict__ Out)
{
    const int tid = threadIdx.x;
    const int w = tid >> 6;
    const int lane = tid & 63;
    const int col = lane & 15, quad = lane >> 4;
    const int it = 3 - (blockIdx.x >> 7);
    const int low = blockIdx.x & 127;
    const int c  = low & 15;
    const int b  = low >> 4;
    const size_t chunk_row = (size_t)b * NN + (size_t)c * CHUNK;
    const size_t bc = ((size_t)(b * NC + c)) << 16;
    const unsigned short* Qrow = PhiQ + (chunk_row + it * 64) * MM;
    const unsigned short* Vf = VTF + bc + (size_t)w * 16384;
    const unsigned short* Sf = STF + bc + (size_t)w * 16384;

    __shared__ unsigned short Qs[64][264];
    __shared__ unsigned short A_s[64][72];
    __shared__ float red[64][68];
    __shared__ float z_s[256];
    __shared__ float den_s[64];

    const float zval = Z[((size_t)(b * NC + c) << 8) + tid];
    s16x8 bk0[8], bk1[8];
#pragma unroll
    for (int ms = 0; ms < 8; ++ms)
        bk0[ms] = *(const s16x8*)(PhiKF + bc + (((size_t)ms * 4 + w) * 64 + lane) * 8);
    uint4 qv[8];
#pragma unroll
    for (int i = 0; i < 8; ++i)
        qv[i] = *((const uint4*)Qrow + i * 256 + tid);
    z_s[tid] = zval;
#pragma unroll
    for (int i = 0; i < 8; ++i) {
        const int f = i * 256 + tid;
        *(uint4*)&Qs[f >> 5][(f & 31) * 8] = qv[i];
    }
    __syncthreads();

    f32x4 oacc[4][4] = {};
    float rsum[4][4] = {};

    for (int jt = 0; jt <= it; ++jt) {
        s16x8 bv[8];
#pragma unroll
        for (int ks2 = 0; ks2 < 2; ++ks2)
#pragma unroll
            for (int t2 = 0; t2 < 4; ++t2)
                bv[ks2 * 4 + t2] = *(const s16x8*)(Vf + (((size_t)(jt * 2 + ks2) * 4 + t2) * 64 + lane) * 8);
        f32x4 accA[4] = {};
#pragma unroll
        for (int ms = 0; ms < 8; ++ms)
#pragma unroll
            for (int t = 0; t < 4; ++t) {
                const s16x8 aq = *(const s16x8*)&Qs[t * 16 + col][ms * 32 + quad * 8];
                accA[t] = MFMA16(aq, bk0[ms], accA[t]);
            }
        if (jt < it) {
#pragma unroll
            for (int ms = 0; ms < 8; ++ms)
                bk1[ms] = *(const s16x8*)(PhiKF + bc + (((size_t)((jt + 1) * 8 + ms) * 4 + w) * 64 + lane) * 8);
        }
        __syncthreads();
#pragma unroll
        for (int t = 0; t < 4; ++t)
#pragma unroll
            for (int r = 0; r < 4; ++r) {
                const int i_loc = t * 16 + quad * 4 + r;
                const int j_loc = w * 16 + col;
                float v = (jt * 64 + j_loc <= it * 64 + i_loc) ? accA[t][r] : 0.f;
                rsum[t][r] += v;
                A_s[i_loc][j_loc] = f2bf(v);
            }
        __syncthreads();
#pragma unroll
        for (int ks2 = 0; ks2 < 2; ++ks2) {
            s16x8 av[4];
#pragma unroll
            for (int t = 0; t < 4; ++t)
                av[t] = *(const s16x8*)&A_s[t * 16 + col][ks2 * 32 + quad * 8];
#pragma unroll
            for (int t2 = 0; t2 < 4; ++t2)
#pragma unroll
                for (int t = 0; t < 4; ++t)
                    oacc[t][t2] = MFMA16(av[t], bv[ks2 * 4 + t2], oacc[t][t2]);
        }
#pragma unroll
        for (int ms = 0; ms < 8; ++ms) bk0[ms] = bk1[ms];
    }
#pragma unroll
    for (int t = 0; t < 4; ++t)
#pragma unroll
        for (int r = 0; r < 4; ++r)
            red[t * 16 + quad * 4 + r][w * 16 + col] = rsum[t][r];

    s16x8 bs0[4], bs1[4];
#pragma unroll
    for (int t2 = 0; t2 < 4; ++t2)
        bs0[t2] = *(const s16x8*)(Sf + ((size_t)t2 * 64 + lane) * 8);
#pragma unroll
    for (int ms = 0; ms < 8; ++ms) {
        if (ms < 7) {
#pragma unroll
            for (int t2 = 0; t2 < 4; ++t2)
                bs1[t2] = *(const s16x8*)(Sf + ((size_t)((ms + 1) * 4 + t2) * 64 + lane) * 8);
        }
        s16x8 aq[4];
#pragma unroll
        for (int t = 0; t < 4; ++t)
            aq[t] = *(const s16x8*)&Qs[t * 16 + col][ms * 32 + quad * 8];
#pragma unroll
        for (int t2 = 0; t2 < 4; ++t2)
#pragma unroll
            for (int t = 0; t < 4; ++t)
                oacc[t][t2] = MFMA16(aq[t], bs0[t2], oacc[t][t2]);
#pragma unroll
        for (int t2 = 0; t2 < 4; ++t2) bs0[t2] = bs1[t2];
    }
    {
        const int i = tid & 63;
        const int seg = tid >> 6;
        float d = 0.f;
#pragma unroll
        for (int g = 0; g < 8; ++g) {
            const s16x8 qv8 = *(const s16x8*)&Qs[i][seg * 64 + g * 8];
#pragma unroll
            for (int x = 0; x < 8; ++x)
                d = fmaf(bf2f((unsigned short)qv8[x]), z_s[seg * 64 + g * 8 + x], d);
        }
        red[i][64 + seg] = d;
    }
    __syncthreads();
    if (tid < 64) {
        float s = 0.f;
#pragma unroll
        for (int j = 0; j < 68; ++j) s += red[tid][j];
        den_s[tid] = fmaxf(s, 1e-6f);
    }
    __syncthreads();
#pragma unroll
    for (int t = 0; t < 4; ++t)
#pragma unroll
        for (int r = 0; r < 4; ++r) {
            const int i_loc = t * 16 + quad * 4 + r;
            const float invd = 1.0f / den_s[i_loc];
#pragma unroll
            for (int t2 = 0; t2 < 4; ++t2)
                Out[(chunk_row + it * 64 + i_loc) * DV + w * 64 + t2 * 16 + col] = oacc[t][t2][r] * invd;
        }
}

extern "C" void kernel_launch(void* const* d_in, const int* in_sizes, int n_in,
                              void* d_out, int out_size, void* d_ws, size_t ws_size,
                              hipStream_t stream)
{
    const float* Q  = (const float*)d_in[0];
    const float* K  = (const float*)d_in[1];
    const float* V  = (const float*)d_in[2];
    const float* Om = (const float*)d_in[3];
    float* out = (float*)d_out;

    const size_t NM = (size_t)BN * NN * MM;
    unsigned short* PhiQ  = (unsigned short*)d_ws;
    unsigned short* PhiKF = PhiQ + NM;
    unsigned short* PhiTF = PhiKF + NM;
    unsigned short* VTF   = PhiTF + NM;
    unsigned short* STF   = VTF + NM;
    unsigned short* OmH   = STF + (size_t)BN * NC * DV * MM;
    unsigned short* OmL   = OmH + (size_t)MM * DD;
    float* Z = (float*)(OmL + (size_t)MM * DD);

    hipMemsetAsync(Z, 0, (size_t)BN * NC * MM * sizeof(float), stream);
    omconv<<<dim3(64), dim3(256), 0, stream>>>(Om, OmH, OmL);
    phi_fused<<<dim3(2048), dim3(256), 0, stream>>>(Q, K, OmH, OmL, PhiQ, PhiKF, PhiTF, Z);
    transpose_v<<<dim3((BN * NN) / 64 * 4), dim3(256), 0, stream>>>(V, VTF);
    state_mfma<<<dim3(BN * NC * 4), dim3(256), 0, stream>>>(VTF, PhiTF, STF);
    prefix2<<<dim3((BN * DV * MM) / 256), dim3(256), 0, stream>>>(STF, Z);
    out_mfma<<<dim3(BN * NC * 4), dim3(256), 0, stream>>>(PhiQ, PhiKF, VTF, STF, Z, out);
}